// Round 16
// baseline (1643.867 us; speedup 1.0000x reference)
//
#include <hip/hip_runtime.h>
#include <hip/hip_bf16.h>

typedef __attribute__((ext_vector_type(4))) float f32x4;
typedef __attribute__((ext_vector_type(8))) short bf16x8;
typedef __attribute__((ext_vector_type(4))) short s16x4;

#define SLOT (1024 * 1024)   // elements per 2MB bf16 power slot

__device__ __forceinline__ short f2bfs(float f) {
  __hip_bfloat16 h = __float2bfloat16(f);   // RNE
  union { __hip_bfloat16 h; short s; } u; u.h = h;
  return u.s;
}
__device__ __forceinline__ float bf2fs(short s) {
  union { unsigned u; float f; } v; v.u = ((unsigned)(unsigned short)s) << 16;
  return v.f;
}

// async global->LDS, 16B/lane; LDS dest linear (wave base + lane*16)
__device__ __forceinline__ void gload16(void* l, const void* g) {
  __builtin_amdgcn_global_load_lds(
      (const __attribute__((address_space(1))) unsigned int*)g,
      (__attribute__((address_space(3))) unsigned int*)l, 16, 0, 0);
}

// RM=0 identity; RM=2 seg-major radix-2: mul=((R>>6)<<7)|(R&63)
// RM=3 C=4 chunk view of XB: row=(R&63)*512 + (R>>6)*4 (K-blocks = next rows)
template<int RM>
__device__ __forceinline__ int rmap(int R) {
  return (RM == 0) ? R
       : (RM == 3) ? (((R & 63) << 9) | ((R >> 6) << 2))
                   : (((R >> 6) << 7) | (R & 63));
}

// ===========================================================================
// epilogue (shared): C/D layout col=lane&15, row=(lane>>4)*4+reg [HW-verified]
// wm=wave>>1, wn=wave&1 (works for 4-wave d4 and 8-wave 8ph decompositions).
// ADD: 0 none; 2 seg add (row+64, bf16). OUT: 0 bf16; 1 fp32
// ===========================================================================
template<int ADD, int OUT>
__device__ __forceinline__ void epi128(
    f32x4 (&acc)[4][4], void* __restrict__ Cp, int ldc,
    const short* __restrict__ AddP,
    int row0, int col0, int M, int wave, int lane) {
  const int wm = wave >> 1, wn = wave & 1;
  const int l16 = lane & 15;
  #pragma unroll
  for (int m = 0; m < 4; ++m) {
    #pragma unroll
    for (int n = 0; n < 4; ++n) {
      const int grow0 = row0 + wm * 64 + m * 16 + ((lane >> 4) << 2);
      const int gcol  = col0 + wn * 64 + n * 16 + l16;
      #pragma unroll
      for (int r = 0; r < 4; ++r) {
        const int R = grow0 + r;
        if (R < M) {
          float val = acc[m][n][r];
          if (ADD == 2) {
            int ar = (((R >> 6) << 7) | (R & 63)) + 64;
            val += bf2fs(AddP[(size_t)ar * 1024 + gcol]);
          }
          if (OUT == 0) ((short*)Cp)[(size_t)R * ldc + gcol] = f2bfs(val);
          else          ((float*)Cp)[(size_t)R * ldc + gcol] = val;
        }
      }
    }
  }
}

// ===========================================================================
// d4 core (proven r12 tree): 128x128 tile, 256 thr, 4 waves 2x2. Depth-4
// counted-vmcnt pipeline: 5 LDS buffers (80KB -> 2 blocks/CU), stage t+4,
// wait vmcnt(min(12, 4*(nkt-1-t))) -> tile t landed, 3 tiles in flight.
// ===========================================================================
struct TileAddr {
  const short *a0, *a1, *b0, *b1;
  int dA0, dA1, dB0, dB1;
  int offA[4], offB[4];
};
template<int RM>
__device__ __forceinline__ TileAddr mk_addr(
    const short* A, int lda, const short* BT, int ldb,
    int row0, int col0, int tid, int wave, int lane) {
  TileAddr t;
  const int wm = wave >> 1, wn = wave & 1;
  const int l16 = lane & 15, kg = lane >> 4;
  const int r0 = tid >> 2, g0 = tid & 3;
  const int gs0 = g0 ^ ((r0 >> 1) & 3);
  const int r1 = r0 + 64;
  const int gs1 = g0 ^ ((r1 >> 1) & 3);
  t.a0 = A + (size_t)rmap<RM>(row0 + r0) * lda + gs0 * 8;
  t.a1 = A + (size_t)rmap<RM>(row0 + r1) * lda + gs1 * 8;
  t.b0 = BT + (size_t)(col0 + r0) * ldb + gs0 * 8;
  t.b1 = BT + (size_t)(col0 + r1) * ldb + gs1 * 8;
  t.dA0 = tid * 16; t.dA1 = t.dA0 + 4096;
  t.dB0 = 8192 + tid * 16; t.dB1 = t.dB0 + 4096;
  #pragma unroll
  for (int m = 0; m < 4; ++m) {
    int row = wm * 64 + m * 16 + l16;
    t.offA[m] = (row * 4 + (kg ^ ((row >> 1) & 3))) * 16;
  }
  #pragma unroll
  for (int n = 0; n < 4; ++n) {
    int c = wn * 64 + n * 16 + l16;
    t.offB[n] = 8192 + (c * 4 + (kg ^ ((c >> 1) & 3))) * 16;
  }
  return t;
}
__device__ __forceinline__ void stage_to(const TileAddr& ta, char* buf, int ko) {
  gload16(buf + ta.dA0, ta.a0 + ko); gload16(buf + ta.dA1, ta.a1 + ko);
  gload16(buf + ta.dB0, ta.b0 + ko); gload16(buf + ta.dB1, ta.b1 + ko);
}
__device__ __forceinline__ void compute_step(
    const TileAddr& ta, const char* buf, f32x4 (&acc)[4][4]) {
  bf16x8 af[4], bfr[4];
  #pragma unroll
  for (int m = 0; m < 4; ++m) af[m] = *(const bf16x8*)(buf + ta.offA[m]);
  #pragma unroll
  for (int n = 0; n < 4; ++n) bfr[n] = *(const bf16x8*)(buf + ta.offB[n]);
  __builtin_amdgcn_s_setprio(1);
  #pragma unroll
  for (int m = 0; m < 4; ++m)
    #pragma unroll
    for (int n = 0; n < 4; ++n)
      acc[m][n] = __builtin_amdgcn_mfma_f32_16x16x32_bf16(af[m], bfr[n], acc[m][n], 0, 0, 0);
  __builtin_amdgcn_s_setprio(0);
}
template<int RM>
__device__ __forceinline__ void gemm128_d4(
    char* lds, f32x4 (&acc)[4][4],
    const short* __restrict__ A, int lda,
    const short* __restrict__ BT, int ldb,
    int row0, int col0, int nkt, int tid, int wave, int lane) {
  TileAddr ta = mk_addr<RM>(A, lda, BT, ldb, row0, col0, tid, wave, lane);
  #pragma unroll
  for (int p = 0; p < 4; ++p)
    stage_to(ta, lds + p * 16384, p * 32);
  int bufc = 0, bufn = 4;   // buf index of tile t, and of tile t+4 (mod 5)
  for (int t = 0; t < nkt; ++t) {
    const int w = nkt - 1 - t;
    if (w >= 3)      { asm volatile("s_waitcnt vmcnt(12)" ::: "memory"); }
    else if (w == 2) { asm volatile("s_waitcnt vmcnt(8)" ::: "memory"); }
    else if (w == 1) { asm volatile("s_waitcnt vmcnt(4)" ::: "memory"); }
    else             { asm volatile("s_waitcnt vmcnt(0)" ::: "memory"); }
    __builtin_amdgcn_s_barrier();
    asm volatile("" ::: "memory");
    if (t + 4 < nkt) stage_to(ta, lds + bufn * 16384, (t + 4) * 32);
    compute_step(ta, lds + bufc * 16384, acc);
    bufc = (bufc == 4) ? 0 : bufc + 1;
    bufn = (bufn == 4) ? 0 : bufn + 1;
  }
}
__device__ __forceinline__ void run_unit_d4(char* lds,
    const short* A, const short* BT, short* C, int ldc,
    int tile, int tid, int wave, int lane) {
  f32x4 acc[4][4] = {};
  int row0 = (tile >> 3) * 128, col0 = (tile & 7) * 128;
  gemm128_d4<0>(lds, acc, A, 1024, BT, 1024, row0, col0, 32, tid, wave, lane);
  epi128<0, 0>(acc, C, ldc, nullptr, row0, col0, 1024, wave, lane);
}

// ===========================================================================
// 8ph core (proven r10-r15 on big GEMMs): 256x128 tile, 512 thr, 8 waves.
// BK=64; 2 fine phases per K-tile; A triple-buffered, B double-buffered;
// vmcnt(6) at Q0 (6 newest = SA(kt+1)+SB(kt+1)); vmcnt(0) final tile.
// LDS: A 3x32KB [0,98304) + B 2x16KB [98304,131072).
// ===========================================================================
template<int RM>
__device__ __forceinline__ void gemm8ph(
    char* lds, f32x4 (&acc)[4][4],
    const short* __restrict__ A, int lda,
    const short* __restrict__ BT, int ldb,
    int row0, int col0, int nkt, int tid, int wave, int lane) {
  const int wm = wave >> 1, wn = wave & 1;
  const int l16 = lane & 15, kg = (lane >> 4) & 3;

  const short* aP[2][2];
  #pragma unroll
  for (int l = 0; l < 2; ++l) {
    int G = l * 512 + tid;
    int rp = G >> 3, gs = (G & 7) ^ (rp & 7);
    #pragma unroll
    for (int h = 0; h < 2; ++h)
      aP[l][h] = A + (size_t)rmap<RM>(row0 + h * 128 + rp) * lda + gs * 8;
  }
  const short* bP[2];
  {
    int rp = tid >> 3, gs = (tid & 7) ^ (rp & 7);
    #pragma unroll
    for (int h = 0; h < 2; ++h)
      bP[h] = BT + (size_t)(col0 + h * 64 + rp) * ldb + gs * 8;
  }

  int offA[4][2], offB[4][2];
  #pragma unroll
  for (int m = 0; m < 4; ++m) {
    int rp = (wm & 1) * 64 + m * 16 + l16;
    #pragma unroll
    for (int ks = 0; ks < 2; ++ks) {
      int gsrc = ks * 4 + kg;
      offA[m][ks] = (wm >> 1) * 16384 + (rp * 8 + (gsrc ^ (rp & 7))) * 16;
    }
  }
  #pragma unroll
  for (int n = 0; n < 4; ++n) {
    int rp = n * 16 + l16;
    #pragma unroll
    for (int ks = 0; ks < 2; ++ks) {
      int gsrc = ks * 4 + kg;
      offB[n][ks] = wn * 8192 + (rp * 8 + (gsrc ^ (rp & 7))) * 16;
    }
  }

  auto SA = [&](int kt, int ad_t, int h) {
    char* dst = lds + ad_t * 32768 + h * 16384 + tid * 16;
    gload16(dst,        aP[0][h] + kt * 64);
    gload16(dst + 8192, aP[1][h] + kt * 64);
  };
  auto SB = [&](int kt, int h) {
    gload16(lds + 98304 + (kt & 1) * 16384 + h * 8192 + tid * 16,
            bP[h] + kt * 64);
  };

  SA(0, 0, 0); SA(0, 0, 1);
  SB(0, 0); SB(0, 1);
  SA(1, 1, 0); SA(1, 1, 1);
  SB(1, 0); SB(1, 1);

  bf16x8 bR[4][2];
  int ad = 0;
  for (int kt = 0; kt < nkt; ++kt) {
    char* baseA = lds + ad * 32768;
    char* baseB = lds + 98304 + (kt & 1) * 16384;
    const int ad2 = (ad >= 1) ? ad - 1 : 2;
    // ---------------- phase Q0 ----------------
    if (kt == nkt - 1) { asm volatile("s_waitcnt vmcnt(0)" ::: "memory"); }
    else               { asm volatile("s_waitcnt vmcnt(6)" ::: "memory"); }
    __builtin_amdgcn_s_barrier();
    __builtin_amdgcn_sched_barrier(0);
    {
      #pragma unroll
      for (int n = 0; n < 4; ++n)
        #pragma unroll
        for (int ks = 0; ks < 2; ++ks)
          bR[n][ks] = *(const bf16x8*)(baseB + offB[n][ks]);
      bf16x8 aR[2][2];
      #pragma unroll
      for (int mm = 0; mm < 2; ++mm)
        #pragma unroll
        for (int ks = 0; ks < 2; ++ks)
          aR[mm][ks] = *(const bf16x8*)(baseA + offA[mm][ks]);
      if (kt + 2 < nkt) { SA(kt + 2, ad2, 0); SA(kt + 2, ad2, 1); }
      __builtin_amdgcn_s_setprio(1);
      #pragma unroll
      for (int mm = 0; mm < 2; ++mm)
        #pragma unroll
        for (int n = 0; n < 4; ++n)
          #pragma unroll
          for (int ks = 0; ks < 2; ++ks)
            acc[mm][n] = __builtin_amdgcn_mfma_f32_16x16x32_bf16(
                aR[mm][ks], bR[n][ks], acc[mm][n], 0, 0, 0);
      __builtin_amdgcn_s_setprio(0);
    }
    // ---------------- phase Q1 ----------------
    __builtin_amdgcn_s_barrier();
    __builtin_amdgcn_sched_barrier(0);
    {
      bf16x8 aR[2][2];
      #pragma unroll
      for (int mm = 0; mm < 2; ++mm)
        #pragma unroll
        for (int ks = 0; ks < 2; ++ks)
          aR[mm][ks] = *(const bf16x8*)(baseA + offA[2 + mm][ks]);
      if (kt + 2 < nkt) { SB(kt + 2, 0); SB(kt + 2, 1); }
      __builtin_amdgcn_s_setprio(1);
      #pragma unroll
      for (int mm = 0; mm < 2; ++mm)
        #pragma unroll
        for (int n = 0; n < 4; ++n)
          #pragma unroll
          for (int ks = 0; ks < 2; ++ks)
            acc[2 + mm][n] = __builtin_amdgcn_mfma_f32_16x16x32_bf16(
                aR[mm][ks], bR[n][ks], acc[2 + mm][n], 0, 0, 0);
      __builtin_amdgcn_s_setprio(0);
    }
    ad = (ad == 2) ? 0 : ad + 1;
  }
}

// 1024x1024 unit on the 8ph core: C = A * BT^T, 32 tiles of 256x128
__device__ __forceinline__ void run_unit8(char* lds,
    const short* A, const short* BT, short* C, int ldc,
    int tile, int tid, int wave, int lane) {
  f32x4 acc[4][4] = {};
  int row0 = (tile >> 3) * 256, col0 = (tile & 7) * 128;
  gemm8ph<0>(lds, acc, A, 1024, BT, 1024, row0, col0, 16, tid, wave, lane);
  epi128<0, 0>(acc, C, ldc, nullptr, row0, col0, 1024, wave, lane);
}

// Slots: 0 UT, 1 U2T, 2 U4T, 3 U8T, 4 U16T, 5 U32T, 6 U64T, 7 U128T, 8 U256T,
//        9 Ub, 10 U2, 11 U4, 12 U8, 13 U16, 14 U32, 15 U64, 16 WU1/U128, 17 Wb

// ---------------- k_prep_tc: transposes + U/W bf16 casts (no X) -------------
__global__ __launch_bounds__(256) void k_prep_tc(
    const float* __restrict__ W, const float* __restrict__ Uf,
    short* __restrict__ BTcat, short* __restrict__ slab) {
  __shared__ float tf[32][36];
  int b = blockIdx.x, t = threadIdx.x;
  if (b < 2048) {
    const float* src = (b < 1024) ? W : Uf;
    int bb = b & 1023;
    int i0 = (bb >> 5) * 32, j0 = (bb & 31) * 32;
    int r = t >> 3, c = (t & 7) * 4;
    *(f32x4*)&tf[r][c] = *(const f32x4*)(src + (size_t)(i0 + r) * 1024 + j0 + c);
    __syncthreads();
    s16x4 o;
    o.x = f2bfs(tf[c + 0][r]); o.y = f2bfs(tf[c + 1][r]);
    o.z = f2bfs(tf[c + 2][r]); o.w = f2bfs(tf[c + 3][r]);
    if (b < 1024)  // W^T -> BTcat col-block 3 (K idx 3072..4095)
      *(s16x4*)(BTcat + (size_t)(j0 + r) * 4096 + 3072 + i0 + c) = o;
    else           // U^T -> slot 0
      *(s16x4*)(slab + (size_t)(j0 + r) * 1024 + i0 + c) = o;
  } else {
    int q = b - 2048;   // first 512 = U cast (slot 9), next 512 = W cast (17)
    const float* src = (q < 512) ? Uf : W;
    short* dst = slab + (size_t)((q < 512) ? 9 : 17) * SLOT;
    int qq = q & 511;
    size_t base = (size_t)qq * 2048 + (size_t)t * 8;
    f32x4 a = *(const f32x4*)(src + base);
    f32x4 c2 = *(const f32x4*)(src + base + 4);
    bf16x8 o;
    o[0] = f2bfs(a.x);  o[1] = f2bfs(a.y);  o[2] = f2bfs(a.z);  o[3] = f2bfs(a.w);
    o[4] = f2bfs(c2.x); o[5] = f2bfs(c2.y); o[6] = f2bfs(c2.z); o[7] = f2bfs(c2.w);
    *(bf16x8*)(dst + base) = o;
  }
}

// ---------------- k_fuse<PH>: pre units (blocks 0-127) + X-cast half --------
// (r12-proven: latency-bound units ride FREE under the BW-bound cast blocks)
// PH=0: pre1 units {U2T, U2, TW1T->BTcat blk2, WU1} + X floats [0, 16.7M)
// PH=1: pre2 units {TW2T, TW3T, U4T, U4}           + X floats [16.7M, 33.5M)
// X-cast COALESCED: lane reads f32x4 at tid*4 (1KB/wave), writes s16x4 (8B).
template<int PH>
__global__ __launch_bounds__(512) void k_fuse(
    const float* __restrict__ X, short* __restrict__ XB,
    short* slab, short* BTcat) {
  __shared__ __align__(16) char lds[131072];
  int tid = threadIdx.x;
  int b = blockIdx.x;
  short* s = slab;
  if (b < 128) {
    int wave = tid >> 6, lane = tid & 63;
    int u = b >> 5, q = b & 31;
    if (PH == 0) {
      if (u == 0)       // U2T = g(UT, Ub)
        run_unit8(lds, s, s + (size_t)9 * SLOT, s + (size_t)1 * SLOT, 1024, q, tid, wave, lane);
      else if (u == 1)  // U2 = g(Ub, UT)
        run_unit8(lds, s + (size_t)9 * SLOT, s, s + (size_t)10 * SLOT, 1024, q, tid, wave, lane);
      else if (u == 2)  // TW1T = g(UT, Wb) = (WU)^T -> BTcat blk2
        run_unit8(lds, s, s + (size_t)17 * SLOT, BTcat + 2048, 4096, q, tid, wave, lane);
      else              // WU1 = g(Wb, UT) = W*U
        run_unit8(lds, s + (size_t)17 * SLOT, s, s + (size_t)16 * SLOT, 1024, q, tid, wave, lane);
    } else {
      if (u == 0)       // TW2T = g(U2T, Wb)
        run_unit8(lds, s + (size_t)1 * SLOT, s + (size_t)17 * SLOT, BTcat + 1024, 4096, q, tid, wave, lane);
      else if (u == 1)  // TW3T = g(U2T, WU1)
        run_unit8(lds, s + (size_t)1 * SLOT, s + (size_t)16 * SLOT, BTcat, 4096, q, tid, wave, lane);
      else if (u == 2)  // U4T = g(U2T, U2)
        run_unit8(lds, s + (size_t)1 * SLOT, s + (size_t)10 * SLOT, s + (size_t)2 * SLOT, 1024, q, tid, wave, lane);
      else              // U4 = g(U2, U2T)
        run_unit8(lds, s + (size_t)10 * SLOT, s + (size_t)1 * SLOT, s + (size_t)11 * SLOT, 1024, q, tid, wave, lane);
    }
  } else {
    // X-cast: block handles 8192 consecutive floats, fully coalesced
    size_t base = ((size_t)(b - 128 + PH * 2048)) * 8192;
    #pragma unroll
    for (int i = 0; i < 4; ++i) {
      size_t idx = base + (size_t)i * 2048 + (size_t)tid * 4;
      f32x4 v = *(const f32x4*)(X + idx);
      s16x4 o;
      o.x = f2bfs(v.x); o.y = f2bfs(v.y); o.z = f2bfs(v.z); o.w = f2bfs(v.w);
      *(s16x4*)(XB + idx) = o;
    }
  }
}

// ---------------- k_big: F0[8192][1024] = XB_chunk4[8192x4096] * BTcat^T ----
// PURE 256 blocks (no side units -> no stragglers at 1 block/CU)
__global__ __launch_bounds__(512) void k_big(
    const short* __restrict__ XB, const short* __restrict__ BTcat,
    short* __restrict__ FA) {
  __shared__ __align__(16) char lds[131072];
  int tid = threadIdx.x, wave = tid >> 6, lane = tid & 63;
  int c = blockIdx.x;
  int c2 = (c & 7) * 32 + (c >> 3);          // bijective XCD chunking (256%8==0)
  f32x4 acc[4][4] = {};
  int row0 = (c2 >> 3) * 256, col0 = (c2 & 7) * 128;  // col-fastest: L2 A-reuse
  gemm8ph<3>(lds, acc, XB, 1024, BTcat, 4096, row0, col0, 64, tid, wave, lane);
  epi128<0, 0>(acc, FA, 1024, nullptr, row0, col0, 8192, wave, lane);
}

// ===========================================================================
// k_tree: ALL 7 tree levels in ONE launch (384 blocks, 80KB LDS -> 2/CU,
// capacity 512 >= 384 -> every block resident at dispatch -> spin-sync is
// deadlock-free). Phase work byte-identical to the r12 7-launch schedule.
// Inter-phase sync: device-scope fences + atomic counter per boundary.
// ===========================================================================
#define NBLK_TREE 384u

#define TPH(OUTV, Fin, PT, Fout, M_, nComb, sa0,sb0,sc0, sa1,sb1,sc1, nS)   \
  do {                                                                      \
    if (b < (nComb)) {                                                      \
      f32x4 acc[4][4] = {};                                                 \
      int row0 = (b >> 3) * 128, col0 = (b & 7) * 128;                      \
      gemm128_d4<2>(lds, acc, (Fin), 1024, (PT), 1024, row0, col0, 32,      \
                    tid, wave, lane);                                       \
      epi128<2, OUTV>(acc, (Fout), 1024, (Fin), row0, col0, (M_),           \
                      wave, lane);                                          \
    } else if ((nS) >= 1 && b < (nComb) + 64) {                             \
      run_unit_d4(lds, (sa0), (sb0), (sc0), 1024, b - (nComb),              \
                  tid, wave, lane);                                         \
    } else if ((nS) == 2 && b < (nComb) + 128) {                            \
      run_unit_d4(lds, (sa1), (sb1), (sc1), 1024, b - (nComb) - 64,         \
                  tid, wave, lane);                                         \
    }                                                                       \
  } while (0)

#define GSYNC(p)                                                            \
  do {                                                                      \
    __threadfence();            /* release: flush to device scope */        \
    __syncthreads();            /* all waves' stores drained (vmcnt) */     \
    if (tid == 0) {                                                         \
      __hip_atomic_fetch_add(&cnt[p], 1u, __ATOMIC_ACQ_REL,                 \
                             __HIP_MEMORY_SCOPE_AGENT);                     \
      while (__hip_atomic_load(&cnt[p], __ATOMIC_ACQUIRE,                   \
                               __HIP_MEMORY_SCOPE_AGENT) < NBLK_TREE)       \
        __builtin_amdgcn_s_sleep(8);                                        \
    }                                                                       \
    __syncthreads();                                                        \
    __threadfence();            /* acquire: invalidate stale lines */       \
  } while (0)

__global__ __launch_bounds__(256) void k_tree(
    short* FA, short* FB, short* slab, float* outp, unsigned* cnt) {
  __shared__ __align__(16) char lds[81920];
  int tid = threadIdx.x, wave = tid >> 6, lane = tid & 63;
  int b = blockIdx.x;
  short* s = slab;
  auto sl = [&](int i) { return s + (size_t)i * SLOT; };

  // ph0: M=4096, nComb=256 (P=U4T); sides U8T=g(U4T,U4), U8=g(U4,U4T)
  TPH(0, FA, sl(2), FB, 4096, 256, sl(2), sl(11), sl(3), sl(11), sl(2), sl(12), 2);
  GSYNC(0);
  // ph1: M=2048, nComb=128 (P=U8T); sides U16T, U16
  TPH(0, FB, sl(3), FA, 2048, 128, sl(3), sl(12), sl(4), sl(12), sl(3), sl(13), 2);
  GSYNC(1);
  // ph2: M=1024, nComb=64 (P=U16T); sides U32T, U32
  TPH(0, FA, sl(4), FB, 1024, 64, sl(4), sl(13), sl(5), sl(13), sl(4), sl(14), 2);
  GSYNC(2);
  // ph3: M=512, nComb=32 (P=U32T); sides U64T, U64
  TPH(0, FB, sl(5), FA, 512, 32, sl(5), sl(14), sl(6), sl(14), sl(5), sl(15), 2);
  GSYNC(3);
  // ph4: M=256, nComb=16 (P=U64T); sides U128T, U128 (slot16, WU1 dead)
  TPH(0, FA, sl(6), FB, 256, 16, sl(6), sl(15), sl(7), sl(15), sl(6), sl(16), 2);
  GSYNC(4);
  // ph5: M=128, nComb=8 (P=U128T); side U256T=g(U128T,U128)
  TPH(0, FB, sl(7), FA, 128, 8, sl(7), sl(16), sl(8), nullptr, nullptr, nullptr, 1);
  GSYNC(5);
  // ph6: M=64, nComb=8 (P=U256T), fp32 -> d_out
  TPH(1, FA, sl(8), outp, 64, 8, nullptr, nullptr, nullptr, nullptr, nullptr, nullptr, 0);
}

extern "C" void kernel_launch(void* const* d_in, const int* in_sizes, int n_in,
                              void* d_out, int out_size, void* d_ws, size_t ws_size,
                              hipStream_t stream) {
  const float* X = (const float*)d_in[0];   // [64,512,1024] fp32
  const float* W = (const float*)d_in[1];   // [1024,1024] fp32
  const float* U = (const float*)d_in[2];   // [1024,1024] fp32
  float* outp = (float*)d_out;              // [64,1024] fp32

  char* ws = (char*)d_ws;
  short* XB    = (short*)ws;                          // [0,64MB) bf16 X
  short* FB    = (short*)ws;                          // aliases XB (dead after k_big)
  short* BTcat = (short*)(ws + ((size_t)64 << 20));   // [64,72) bf16 [1024][4096]
  short* slab  = (short*)(ws + ((size_t)72 << 20));   // [72,108) 18 x 2MB slots
  short* FA    = (short*)(ws + ((size_t)108 << 20));  // [108,124) bf16 [8192][1024]
  unsigned* cnt = (unsigned*)(ws + ((size_t)126 << 20)); // 6 phase counters

  hipMemsetAsync(cnt, 0, 8 * sizeof(unsigned), stream);
  k_prep_tc<<<3072, 256, 0, stream>>>(W, U, BTcat, slab);
  k_fuse<0><<<2176, 512, 0, stream>>>(X, XB, slab, BTcat);   // pre1 + X-cast A
  k_fuse<1><<<2176, 512, 0, stream>>>(X, XB, slab, BTcat);   // pre2 + X-cast B
  k_big<<<256, 512, 0, stream>>>(XB, BTcat, FA);
  k_tree<<<NBLK_TREE, 256, 0, stream>>>(FA, FB, slab, outp, cnt);
}

// Round 17
// 323.281 us; speedup vs baseline: 5.0850x; 5.0850x over previous
//
#include <hip/hip_runtime.h>
#include <hip/hip_bf16.h>

typedef __attribute__((ext_vector_type(4))) float f32x4;
typedef __attribute__((ext_vector_type(8))) short bf16x8;
typedef __attribute__((ext_vector_type(4))) short s16x4;

#define SLOT (1024 * 1024)   // elements per 2MB bf16 power slot

__device__ __forceinline__ short f2bfs(float f) {
  __hip_bfloat16 h = __float2bfloat16(f);   // RNE
  union { __hip_bfloat16 h; short s; } u; u.h = h;
  return u.s;
}
__device__ __forceinline__ float bf2fs(short s) {
  union { unsigned u; float f; } v; v.u = ((unsigned)(unsigned short)s) << 16;
  return v.f;
}

// async global->LDS, 16B/lane; LDS dest linear (wave base + lane*16)
__device__ __forceinline__ void gload16(void* l, const void* g) {
  __builtin_amdgcn_global_load_lds(
      (const __attribute__((address_space(1))) unsigned int*)g,
      (__attribute__((address_space(3))) unsigned int*)l, 16, 0, 0);
}

// RM=0 identity; RM=2 seg-major radix-2: mul=((R>>6)<<7)|(R&63)
// RM=3 C=4 chunk view of XB: row=(R&63)*512 + (R>>6)*4 (K-blocks = next rows)
template<int RM>
__device__ __forceinline__ int rmap(int R) {
  return (RM == 0) ? R
       : (RM == 3) ? (((R & 63) << 9) | ((R >> 6) << 2))
                   : (((R >> 6) << 7) | (R & 63));
}

// ===========================================================================
// epilogue (shared): C/D layout col=lane&15, row=(lane>>4)*4+reg [HW-verified]
// wm=wave>>1, wn=wave&1 (works for 4-wave d4 and 8-wave 8ph decompositions).
// ADD: 0 none; 2 seg add (row+64, bf16). OUT: 0 bf16; 1 fp32
// ===========================================================================
template<int ADD, int OUT>
__device__ __forceinline__ void epi128(
    f32x4 (&acc)[4][4], void* __restrict__ Cp, int ldc,
    const short* __restrict__ AddP,
    int row0, int col0, int M, int wave, int lane) {
  const int wm = wave >> 1, wn = wave & 1;
  const int l16 = lane & 15;
  #pragma unroll
  for (int m = 0; m < 4; ++m) {
    #pragma unroll
    for (int n = 0; n < 4; ++n) {
      const int grow0 = row0 + wm * 64 + m * 16 + ((lane >> 4) << 2);
      const int gcol  = col0 + wn * 64 + n * 16 + l16;
      #pragma unroll
      for (int r = 0; r < 4; ++r) {
        const int R = grow0 + r;
        if (R < M) {
          float val = acc[m][n][r];
          if (ADD == 2) {
            int ar = (((R >> 6) << 7) | (R & 63)) + 64;
            val += bf2fs(AddP[(size_t)ar * 1024 + gcol]);
          }
          if (OUT == 0) ((short*)Cp)[(size_t)R * ldc + gcol] = f2bfs(val);
          else          ((float*)Cp)[(size_t)R * ldc + gcol] = val;
        }
      }
    }
  }
}

// ===========================================================================
// d4 core (proven r12): 128x128 tile, 256 thr, 4 waves 2x2. Depth-4
// counted-vmcnt pipeline: 5 LDS buffers (80KB -> 2 blocks/CU), stage t+4,
// wait vmcnt(min(12, 4*(nkt-1-t))) -> tile t landed, 3 tiles in flight.
// ===========================================================================
struct TileAddr {
  const short *a0, *a1, *b0, *b1;
  int dA0, dA1, dB0, dB1;
  int offA[4], offB[4];
};
template<int RM>
__device__ __forceinline__ TileAddr mk_addr(
    const short* A, int lda, const short* BT, int ldb,
    int row0, int col0, int tid, int wave, int lane) {
  TileAddr t;
  const int wm = wave >> 1, wn = wave & 1;
  const int l16 = lane & 15, kg = lane >> 4;
  const int r0 = tid >> 2, g0 = tid & 3;
  const int gs0 = g0 ^ ((r0 >> 1) & 3);
  const int r1 = r0 + 64;
  const int gs1 = g0 ^ ((r1 >> 1) & 3);
  t.a0 = A + (size_t)rmap<RM>(row0 + r0) * lda + gs0 * 8;
  t.a1 = A + (size_t)rmap<RM>(row0 + r1) * lda + gs1 * 8;
  t.b0 = BT + (size_t)(col0 + r0) * ldb + gs0 * 8;
  t.b1 = BT + (size_t)(col0 + r1) * ldb + gs1 * 8;
  t.dA0 = tid * 16; t.dA1 = t.dA0 + 4096;
  t.dB0 = 8192 + tid * 16; t.dB1 = t.dB0 + 4096;
  #pragma unroll
  for (int m = 0; m < 4; ++m) {
    int row = wm * 64 + m * 16 + l16;
    t.offA[m] = (row * 4 + (kg ^ ((row >> 1) & 3))) * 16;
  }
  #pragma unroll
  for (int n = 0; n < 4; ++n) {
    int c = wn * 64 + n * 16 + l16;
    t.offB[n] = 8192 + (c * 4 + (kg ^ ((c >> 1) & 3))) * 16;
  }
  return t;
}
__device__ __forceinline__ void stage_to(const TileAddr& ta, char* buf, int ko) {
  gload16(buf + ta.dA0, ta.a0 + ko); gload16(buf + ta.dA1, ta.a1 + ko);
  gload16(buf + ta.dB0, ta.b0 + ko); gload16(buf + ta.dB1, ta.b1 + ko);
}
__device__ __forceinline__ void compute_step(
    const TileAddr& ta, const char* buf, f32x4 (&acc)[4][4]) {
  bf16x8 af[4], bfr[4];
  #pragma unroll
  for (int m = 0; m < 4; ++m) af[m] = *(const bf16x8*)(buf + ta.offA[m]);
  #pragma unroll
  for (int n = 0; n < 4; ++n) bfr[n] = *(const bf16x8*)(buf + ta.offB[n]);
  __builtin_amdgcn_s_setprio(1);
  #pragma unroll
  for (int m = 0; m < 4; ++m)
    #pragma unroll
    for (int n = 0; n < 4; ++n)
      acc[m][n] = __builtin_amdgcn_mfma_f32_16x16x32_bf16(af[m], bfr[n], acc[m][n], 0, 0, 0);
  __builtin_amdgcn_s_setprio(0);
}
template<int RM>
__device__ __forceinline__ void gemm128_d4(
    char* lds, f32x4 (&acc)[4][4],
    const short* __restrict__ A, int lda,
    const short* __restrict__ BT, int ldb,
    int row0, int col0, int nkt, int tid, int wave, int lane) {
  TileAddr ta = mk_addr<RM>(A, lda, BT, ldb, row0, col0, tid, wave, lane);
  #pragma unroll
  for (int p = 0; p < 4; ++p)
    stage_to(ta, lds + p * 16384, p * 32);
  int bufc = 0, bufn = 4;   // buf index of tile t, and of tile t+4 (mod 5)
  for (int t = 0; t < nkt; ++t) {
    const int w = nkt - 1 - t;
    if (w >= 3)      { asm volatile("s_waitcnt vmcnt(12)" ::: "memory"); }
    else if (w == 2) { asm volatile("s_waitcnt vmcnt(8)" ::: "memory"); }
    else if (w == 1) { asm volatile("s_waitcnt vmcnt(4)" ::: "memory"); }
    else             { asm volatile("s_waitcnt vmcnt(0)" ::: "memory"); }
    __builtin_amdgcn_s_barrier();
    asm volatile("" ::: "memory");
    if (t + 4 < nkt) stage_to(ta, lds + bufn * 16384, (t + 4) * 32);
    compute_step(ta, lds + bufc * 16384, acc);
    bufc = (bufc == 4) ? 0 : bufc + 1;
    bufn = (bufn == 4) ? 0 : bufn + 1;
  }
}
__device__ __forceinline__ void run_unit_d4(char* lds,
    const short* A, const short* BT, short* C, int ldc,
    int tile, int tid, int wave, int lane) {
  f32x4 acc[4][4] = {};
  int row0 = (tile >> 3) * 128, col0 = (tile & 7) * 128;
  gemm128_d4<0>(lds, acc, A, 1024, BT, 1024, row0, col0, 32, tid, wave, lane);
  epi128<0, 0>(acc, C, ldc, nullptr, row0, col0, 1024, wave, lane);
}

// ===========================================================================
// 8ph core (proven r10-r16 on k_big): 256x128 tile, 512 thr, 8 waves.
// BK=64; 2 fine phases per K-tile; A triple-buffered, B double-buffered;
// vmcnt(6) at Q0 (6 newest = SA(kt+1)+SB(kt+1)); vmcnt(0) final tile.
// LDS: A 3x32KB [0,98304) + B 2x16KB [98304,131072).
// ===========================================================================
template<int RM>
__device__ __forceinline__ void gemm8ph(
    char* lds, f32x4 (&acc)[4][4],
    const short* __restrict__ A, int lda,
    const short* __restrict__ BT, int ldb,
    int row0, int col0, int nkt, int tid, int wave, int lane) {
  const int wm = wave >> 1, wn = wave & 1;
  const int l16 = lane & 15, kg = (lane >> 4) & 3;

  const short* aP[2][2];
  #pragma unroll
  for (int l = 0; l < 2; ++l) {
    int G = l * 512 + tid;
    int rp = G >> 3, gs = (G & 7) ^ (rp & 7);
    #pragma unroll
    for (int h = 0; h < 2; ++h)
      aP[l][h] = A + (size_t)rmap<RM>(row0 + h * 128 + rp) * lda + gs * 8;
  }
  const short* bP[2];
  {
    int rp = tid >> 3, gs = (tid & 7) ^ (rp & 7);
    #pragma unroll
    for (int h = 0; h < 2; ++h)
      bP[h] = BT + (size_t)(col0 + h * 64 + rp) * ldb + gs * 8;
  }

  int offA[4][2], offB[4][2];
  #pragma unroll
  for (int m = 0; m < 4; ++m) {
    int rp = (wm & 1) * 64 + m * 16 + l16;
    #pragma unroll
    for (int ks = 0; ks < 2; ++ks) {
      int gsrc = ks * 4 + kg;
      offA[m][ks] = (wm >> 1) * 16384 + (rp * 8 + (gsrc ^ (rp & 7))) * 16;
    }
  }
  #pragma unroll
  for (int n = 0; n < 4; ++n) {
    int rp = n * 16 + l16;
    #pragma unroll
    for (int ks = 0; ks < 2; ++ks) {
      int gsrc = ks * 4 + kg;
      offB[n][ks] = wn * 8192 + (rp * 8 + (gsrc ^ (rp & 7))) * 16;
    }
  }

  auto SA = [&](int kt, int ad_t, int h) {
    char* dst = lds + ad_t * 32768 + h * 16384 + tid * 16;
    gload16(dst,        aP[0][h] + kt * 64);
    gload16(dst + 8192, aP[1][h] + kt * 64);
  };
  auto SB = [&](int kt, int h) {
    gload16(lds + 98304 + (kt & 1) * 16384 + h * 8192 + tid * 16,
            bP[h] + kt * 64);
  };

  SA(0, 0, 0); SA(0, 0, 1);
  SB(0, 0); SB(0, 1);
  SA(1, 1, 0); SA(1, 1, 1);
  SB(1, 0); SB(1, 1);

  bf16x8 bR[4][2];
  int ad = 0;
  for (int kt = 0; kt < nkt; ++kt) {
    char* baseA = lds + ad * 32768;
    char* baseB = lds + 98304 + (kt & 1) * 16384;
    const int ad2 = (ad >= 1) ? ad - 1 : 2;
    // ---------------- phase Q0 ----------------
    if (kt == nkt - 1) { asm volatile("s_waitcnt vmcnt(0)" ::: "memory"); }
    else               { asm volatile("s_waitcnt vmcnt(6)" ::: "memory"); }
    __builtin_amdgcn_s_barrier();
    __builtin_amdgcn_sched_barrier(0);
    {
      #pragma unroll
      for (int n = 0; n < 4; ++n)
        #pragma unroll
        for (int ks = 0; ks < 2; ++ks)
          bR[n][ks] = *(const bf16x8*)(baseB + offB[n][ks]);
      bf16x8 aR[2][2];
      #pragma unroll
      for (int mm = 0; mm < 2; ++mm)
        #pragma unroll
        for (int ks = 0; ks < 2; ++ks)
          aR[mm][ks] = *(const bf16x8*)(baseA + offA[mm][ks]);
      if (kt + 2 < nkt) { SA(kt + 2, ad2, 0); SA(kt + 2, ad2, 1); }
      __builtin_amdgcn_s_setprio(1);
      #pragma unroll
      for (int mm = 0; mm < 2; ++mm)
        #pragma unroll
        for (int n = 0; n < 4; ++n)
          #pragma unroll
          for (int ks = 0; ks < 2; ++ks)
            acc[mm][n] = __builtin_amdgcn_mfma_f32_16x16x32_bf16(
                aR[mm][ks], bR[n][ks], acc[mm][n], 0, 0, 0);
      __builtin_amdgcn_s_setprio(0);
    }
    // ---------------- phase Q1 ----------------
    __builtin_amdgcn_s_barrier();
    __builtin_amdgcn_sched_barrier(0);
    {
      bf16x8 aR[2][2];
      #pragma unroll
      for (int mm = 0; mm < 2; ++mm)
        #pragma unroll
        for (int ks = 0; ks < 2; ++ks)
          aR[mm][ks] = *(const bf16x8*)(baseA + offA[2 + mm][ks]);
      if (kt + 2 < nkt) { SB(kt + 2, 0); SB(kt + 2, 1); }
      __builtin_amdgcn_s_setprio(1);
      #pragma unroll
      for (int mm = 0; mm < 2; ++mm)
        #pragma unroll
        for (int n = 0; n < 4; ++n)
          #pragma unroll
          for (int ks = 0; ks < 2; ++ks)
            acc[2 + mm][n] = __builtin_amdgcn_mfma_f32_16x16x32_bf16(
                aR[mm][ks], bR[n][ks], acc[2 + mm][n], 0, 0, 0);
      __builtin_amdgcn_s_setprio(0);
    }
    ad = (ad == 2) ? 0 : ad + 1;
  }
}

// Slots: 0 UT, 1 U2T, 2 U4T, 3 U8T, 4 U16T, 5 U32T, 6 U64T, 7 U128T, 8 U256T,
//        9 Ub, 10 U2, 11 U4, 12 U8, 13 U16, 14 U32, 15 U64, 16 WU1/U128, 17 Wb

// ---------------- k_prep_tc: transposes + U/W bf16 casts (no X) -------------
__global__ __launch_bounds__(256) void k_prep_tc(
    const float* __restrict__ W, const float* __restrict__ Uf,
    short* __restrict__ BTcat, short* __restrict__ slab) {
  __shared__ float tf[32][36];
  int b = blockIdx.x, t = threadIdx.x;
  if (b < 2048) {
    const float* src = (b < 1024) ? W : Uf;
    int bb = b & 1023;
    int i0 = (bb >> 5) * 32, j0 = (bb & 31) * 32;
    int r = t >> 3, c = (t & 7) * 4;
    *(f32x4*)&tf[r][c] = *(const f32x4*)(src + (size_t)(i0 + r) * 1024 + j0 + c);
    __syncthreads();
    s16x4 o;
    o.x = f2bfs(tf[c + 0][r]); o.y = f2bfs(tf[c + 1][r]);
    o.z = f2bfs(tf[c + 2][r]); o.w = f2bfs(tf[c + 3][r]);
    if (b < 1024)  // W^T -> BTcat col-block 3 (K idx 3072..4095)
      *(s16x4*)(BTcat + (size_t)(j0 + r) * 4096 + 3072 + i0 + c) = o;
    else           // U^T -> slot 0
      *(s16x4*)(slab + (size_t)(j0 + r) * 1024 + i0 + c) = o;
  } else {
    int q = b - 2048;   // first 512 = U cast (slot 9), next 512 = W cast (17)
    const float* src = (q < 512) ? Uf : W;
    short* dst = slab + (size_t)((q < 512) ? 9 : 17) * SLOT;
    int qq = q & 511;
    size_t base = (size_t)qq * 2048 + (size_t)t * 8;
    f32x4 a = *(const f32x4*)(src + base);
    f32x4 c2 = *(const f32x4*)(src + base + 4);
    bf16x8 o;
    o[0] = f2bfs(a.x);  o[1] = f2bfs(a.y);  o[2] = f2bfs(a.z);  o[3] = f2bfs(a.w);
    o[4] = f2bfs(c2.x); o[5] = f2bfs(c2.y); o[6] = f2bfs(c2.z); o[7] = f2bfs(c2.w);
    *(bf16x8*)(dst + base) = o;
  }
}

// ---------------- k_fuse<PH>: pre units (blocks 0-255, d4 core) + X-cast ----
// d4 units (80KB LDS) so cast blocks run 2/CU (vs 1/CU at 128KB in r12).
// PH=0: pre1 units {U2T, U2, TW1T->BTcat blk2, WU1} + X floats [0, 16.7M)
// PH=1: pre2 units {TW2T, TW3T, U4T, U4}           + X floats [16.7M, 33.5M)
// X-cast COALESCED: lane reads f32x4 at tid*4, writes s16x4 (8B).
template<int PH>
__global__ __launch_bounds__(256) void k_fuse(
    const float* __restrict__ X, short* __restrict__ XB,
    short* slab, short* BTcat) {
  __shared__ __align__(16) char lds[81920];
  int tid = threadIdx.x;
  int b = blockIdx.x;
  short* s = slab;
  if (b < 256) {
    int wave = tid >> 6, lane = tid & 63;
    int u = b >> 6, q = b & 63;
    if (PH == 0) {
      if (u == 0)       // U2T = g(UT, Ub)
        run_unit_d4(lds, s, s + (size_t)9 * SLOT, s + (size_t)1 * SLOT, 1024, q, tid, wave, lane);
      else if (u == 1)  // U2 = g(Ub, UT)
        run_unit_d4(lds, s + (size_t)9 * SLOT, s, s + (size_t)10 * SLOT, 1024, q, tid, wave, lane);
      else if (u == 2)  // TW1T = g(UT, Wb) = (WU)^T -> BTcat blk2
        run_unit_d4(lds, s, s + (size_t)17 * SLOT, BTcat + 2048, 4096, q, tid, wave, lane);
      else              // WU1 = g(Wb, UT) = W*U
        run_unit_d4(lds, s + (size_t)17 * SLOT, s, s + (size_t)16 * SLOT, 1024, q, tid, wave, lane);
    } else {
      if (u == 0)       // TW2T = g(U2T, Wb)
        run_unit_d4(lds, s + (size_t)1 * SLOT, s + (size_t)17 * SLOT, BTcat + 1024, 4096, q, tid, wave, lane);
      else if (u == 1)  // TW3T = g(U2T, WU1)
        run_unit_d4(lds, s + (size_t)1 * SLOT, s + (size_t)16 * SLOT, BTcat, 4096, q, tid, wave, lane);
      else if (u == 2)  // U4T = g(U2T, U2)
        run_unit_d4(lds, s + (size_t)1 * SLOT, s + (size_t)10 * SLOT, s + (size_t)2 * SLOT, 1024, q, tid, wave, lane);
      else              // U4 = g(U2, U2T)
        run_unit_d4(lds, s + (size_t)10 * SLOT, s + (size_t)1 * SLOT, s + (size_t)11 * SLOT, 1024, q, tid, wave, lane);
    }
  } else {
    // X-cast: block handles 8192 consecutive floats, fully coalesced
    size_t base = ((size_t)(b - 256 + PH * 2048)) * 8192;
    #pragma unroll
    for (int i = 0; i < 8; ++i) {
      size_t idx = base + (size_t)i * 1024 + (size_t)tid * 4;
      f32x4 v = *(const f32x4*)(X + idx);
      s16x4 o;
      o.x = f2bfs(v.x); o.y = f2bfs(v.y); o.z = f2bfs(v.z); o.w = f2bfs(v.w);
      *(s16x4*)(XB + idx) = o;
    }
  }
}

// ---------------- k_big: F0[8192][1024] = XB_chunk4[8192x4096] * BTcat^T ----
// PURE 256 blocks; col-per-XCD: blockIdx->XCD is round-robin (c%8), so
// col0=(c&7)*128 pins each XCD to ONE 1MB BTcat column slice (L2-resident).
__global__ __launch_bounds__(512) void k_big(
    const short* __restrict__ XB, const short* __restrict__ BTcat,
    short* __restrict__ FA) {
  __shared__ __align__(16) char lds[131072];
  int tid = threadIdx.x, wave = tid >> 6, lane = tid & 63;
  int c = blockIdx.x;
  f32x4 acc[4][4] = {};
  int row0 = (c >> 3) * 256, col0 = (c & 7) * 128;
  gemm8ph<3>(lds, acc, XB, 1024, BTcat, 4096, row0, col0, 64, tid, wave, lane);
  epi128<0, 0>(acc, FA, 1024, nullptr, row0, col0, 8192, wave, lane);
}

// ---------------- tree level (r12-proven): d4 combine + 0-2 side units ------
// Power chain rides the tree: level k's sides build U^(2^(k+3)) for level k+1.
template<int OUT>
__global__ __launch_bounds__(256) void k_lvl(
    const short* __restrict__ Fin, const short* __restrict__ PT,
    void* __restrict__ Fout, int M, int nComb,
    const short* __restrict__ sA0, const short* __restrict__ sB0, short* __restrict__ sC0,
    const short* __restrict__ sA1, const short* __restrict__ sB1, short* __restrict__ sC1) {
  __shared__ __align__(16) char lds[81920];
  int tid = threadIdx.x, wave = tid >> 6, lane = tid & 63;
  int b = blockIdx.x;
  if (b < nComb) {
    f32x4 acc[4][4] = {};
    int row0 = (b >> 3) * 128, col0 = (b & 7) * 128;
    gemm128_d4<2>(lds, acc, Fin, 1024, PT, 1024, row0, col0, 32, tid, wave, lane);
    epi128<2, OUT>(acc, Fout, 1024, Fin, row0, col0, M, wave, lane);
  } else {
    int q = b - nComb;
    const short* sa = (q < 64) ? sA0 : sA1;
    const short* sb = (q < 64) ? sB0 : sB1;
    short* sc = (q < 64) ? sC0 : sC1;
    run_unit_d4(lds, sa, sb, sc, 1024, q & 63, tid, wave, lane);
  }
}

extern "C" void kernel_launch(void* const* d_in, const int* in_sizes, int n_in,
                              void* d_out, int out_size, void* d_ws, size_t ws_size,
                              hipStream_t stream) {
  const float* X = (const float*)d_in[0];   // [64,512,1024] fp32
  const float* W = (const float*)d_in[1];   // [1024,1024] fp32
  const float* U = (const float*)d_in[2];   // [1024,1024] fp32
  float* outp = (float*)d_out;              // [64,1024] fp32

  char* ws = (char*)d_ws;
  short* XB    = (short*)ws;                          // [0,64MB) bf16 X
  short* FB    = (short*)ws;                          // aliases XB (dead after k_big)
  short* BTcat = (short*)(ws + ((size_t)64 << 20));   // [64,72) bf16 [1024][4096]
  short* slab  = (short*)(ws + ((size_t)72 << 20));   // [72,108) 18 x 2MB slots
  short* FA    = (short*)(ws + ((size_t)108 << 20));  // [108,124) bf16 [8192][1024]
  auto sl = [&](int i) { return slab + (size_t)i * SLOT; };

  k_prep_tc<<<3072, 256, 0, stream>>>(W, U, BTcat, slab);
  k_fuse<0><<<2304, 256, 0, stream>>>(X, XB, slab, BTcat);   // pre1 + X-cast A
  k_fuse<1><<<2304, 256, 0, stream>>>(X, XB, slab, BTcat);   // pre2 + X-cast B
  k_big<<<256, 512, 0, stream>>>(XB, BTcat, FA);

  // ph0: M=4096, nComb=256 (P=U4T); sides U8T=g(U4T,U4), U8=g(U4,U4T)
  k_lvl<0><<<384, 256, 0, stream>>>(FA, sl(2), FB, 4096, 256,
                                    sl(2), sl(11), sl(3), sl(11), sl(2), sl(12));
  // ph1: M=2048, nComb=128 (P=U8T); sides U16T, U16
  k_lvl<0><<<256, 256, 0, stream>>>(FB, sl(3), FA, 2048, 128,
                                    sl(3), sl(12), sl(4), sl(12), sl(3), sl(13));
  // ph2: M=1024, nComb=64 (P=U16T); sides U32T, U32
  k_lvl<0><<<192, 256, 0, stream>>>(FA, sl(4), FB, 1024, 64,
                                    sl(4), sl(13), sl(5), sl(13), sl(4), sl(14));
  // ph3: M=512, nComb=32 (P=U32T); sides U64T, U64
  k_lvl<0><<<160, 256, 0, stream>>>(FB, sl(5), FA, 512, 32,
                                    sl(5), sl(14), sl(6), sl(14), sl(5), sl(15));
  // ph4: M=256, nComb=16 (P=U64T); sides U128T, U128 (U128 -> slot16, WU1 dead)
  k_lvl<0><<<144, 256, 0, stream>>>(FA, sl(6), FB, 256, 16,
                                    sl(6), sl(15), sl(7), sl(15), sl(6), sl(16));
  // ph5: M=128, nComb=8 (P=U128T); side U256T=g(U128T,U128)
  k_lvl<0><<<72, 256, 0, stream>>>(FB, sl(7), FA, 128, 8,
                                   sl(7), sl(16), sl(8), nullptr, nullptr, nullptr);
  // ph6: M=64, nComb=8 (P=U256T), fp32 -> d_out
  k_lvl<1><<<8, 256, 0, stream>>>(FA, sl(8), outp, 64, 8,
                                  nullptr, nullptr, nullptr, nullptr, nullptr, nullptr);
}

// Round 18
// 300.523 us; speedup vs baseline: 5.4700x; 1.0757x over previous
//
#include <hip/hip_runtime.h>
#include <hip/hip_bf16.h>

typedef __attribute__((ext_vector_type(4))) float f32x4;
typedef __attribute__((ext_vector_type(8))) short bf16x8;
typedef __attribute__((ext_vector_type(4))) short s16x4;

#define SLOT (1024 * 1024)   // elements per 2MB bf16 power slot

__device__ __forceinline__ short f2bfs(float f) {
  __hip_bfloat16 h = __float2bfloat16(f);   // RNE
  union { __hip_bfloat16 h; short s; } u; u.h = h;
  return u.s;
}
__device__ __forceinline__ float bf2fs(short s) {
  union { unsigned u; float f; } v; v.u = ((unsigned)(unsigned short)s) << 16;
  return v.f;
}

// async global->LDS, 16B/lane; LDS dest linear (wave base + lane*16)
__device__ __forceinline__ void gload16(void* l, const void* g) {
  __builtin_amdgcn_global_load_lds(
      (const __attribute__((address_space(1))) unsigned int*)g,
      (__attribute__((address_space(3))) unsigned int*)l, 16, 0, 0);
}

// RM=0 identity; RM=2 seg-major radix-2: mul=((R>>6)<<7)|(R&63)
// RM=3 C=4 chunk view of XB: row=(R&63)*512 + (R>>6)*4 (K-blocks = next rows)
template<int RM>
__device__ __forceinline__ int rmap(int R) {
  return (RM == 0) ? R
       : (RM == 3) ? (((R & 63) << 9) | ((R >> 6) << 2))
                   : (((R >> 6) << 7) | (R & 63));
}

// ===========================================================================
// epilogue (shared): C/D layout col=lane&15, row=(lane>>4)*4+reg [HW-verified]
// wm=wave>>1, wn=wave&1 (works for 4-wave d4 and 8-wave 8ph decompositions).
// ADD: 0 none; 2 seg add (row+64, bf16). OUT: 0 bf16; 1 fp32
// ===========================================================================
template<int ADD, int OUT>
__device__ __forceinline__ void epi128(
    f32x4 (&acc)[4][4], void* __restrict__ Cp, int ldc,
    const short* __restrict__ AddP,
    int row0, int col0, int M, int wave, int lane) {
  const int wm = wave >> 1, wn = wave & 1;
  const int l16 = lane & 15;
  #pragma unroll
  for (int m = 0; m < 4; ++m) {
    #pragma unroll
    for (int n = 0; n < 4; ++n) {
      const int grow0 = row0 + wm * 64 + m * 16 + ((lane >> 4) << 2);
      const int gcol  = col0 + wn * 64 + n * 16 + l16;
      #pragma unroll
      for (int r = 0; r < 4; ++r) {
        const int R = grow0 + r;
        if (R < M) {
          float val = acc[m][n][r];
          if (ADD == 2) {
            int ar = (((R >> 6) << 7) | (R & 63)) + 64;
            val += bf2fs(AddP[(size_t)ar * 1024 + gcol]);
          }
          if (OUT == 0) ((short*)Cp)[(size_t)R * ldc + gcol] = f2bfs(val);
          else          ((float*)Cp)[(size_t)R * ldc + gcol] = val;
        }
      }
    }
  }
}

// ===========================================================================
// d4 core (proven r12 tree): 128x128 tile, 256 thr, 4 waves 2x2. Depth-4
// counted-vmcnt pipeline: 5 LDS buffers (80KB -> 2 blocks/CU), stage t+4,
// wait vmcnt(min(12, 4*(nkt-1-t))) -> tile t landed, 3 tiles in flight.
// ===========================================================================
struct TileAddr {
  const short *a0, *a1, *b0, *b1;
  int dA0, dA1, dB0, dB1;
  int offA[4], offB[4];
};
template<int RM>
__device__ __forceinline__ TileAddr mk_addr(
    const short* A, int lda, const short* BT, int ldb,
    int row0, int col0, int tid, int wave, int lane) {
  TileAddr t;
  const int wm = wave >> 1, wn = wave & 1;
  const int l16 = lane & 15, kg = lane >> 4;
  const int r0 = tid >> 2, g0 = tid & 3;
  const int gs0 = g0 ^ ((r0 >> 1) & 3);
  const int r1 = r0 + 64;
  const int gs1 = g0 ^ ((r1 >> 1) & 3);
  t.a0 = A + (size_t)rmap<RM>(row0 + r0) * lda + gs0 * 8;
  t.a1 = A + (size_t)rmap<RM>(row0 + r1) * lda + gs1 * 8;
  t.b0 = BT + (size_t)(col0 + r0) * ldb + gs0 * 8;
  t.b1 = BT + (size_t)(col0 + r1) * ldb + gs1 * 8;
  t.dA0 = tid * 16; t.dA1 = t.dA0 + 4096;
  t.dB0 = 8192 + tid * 16; t.dB1 = t.dB0 + 4096;
  #pragma unroll
  for (int m = 0; m < 4; ++m) {
    int row = wm * 64 + m * 16 + l16;
    t.offA[m] = (row * 4 + (kg ^ ((row >> 1) & 3))) * 16;
  }
  #pragma unroll
  for (int n = 0; n < 4; ++n) {
    int c = wn * 64 + n * 16 + l16;
    t.offB[n] = 8192 + (c * 4 + (kg ^ ((c >> 1) & 3))) * 16;
  }
  return t;
}
__device__ __forceinline__ void stage_to(const TileAddr& ta, char* buf, int ko) {
  gload16(buf + ta.dA0, ta.a0 + ko); gload16(buf + ta.dA1, ta.a1 + ko);
  gload16(buf + ta.dB0, ta.b0 + ko); gload16(buf + ta.dB1, ta.b1 + ko);
}
__device__ __forceinline__ void compute_step(
    const TileAddr& ta, const char* buf, f32x4 (&acc)[4][4]) {
  bf16x8 af[4], bfr[4];
  #pragma unroll
  for (int m = 0; m < 4; ++m) af[m] = *(const bf16x8*)(buf + ta.offA[m]);
  #pragma unroll
  for (int n = 0; n < 4; ++n) bfr[n] = *(const bf16x8*)(buf + ta.offB[n]);
  __builtin_amdgcn_s_setprio(1);
  #pragma unroll
  for (int m = 0; m < 4; ++m)
    #pragma unroll
    for (int n = 0; n < 4; ++n)
      acc[m][n] = __builtin_amdgcn_mfma_f32_16x16x32_bf16(af[m], bfr[n], acc[m][n], 0, 0, 0);
  __builtin_amdgcn_s_setprio(0);
}
template<int RM>
__device__ __forceinline__ void gemm128_d4(
    char* lds, f32x4 (&acc)[4][4],
    const short* __restrict__ A, int lda,
    const short* __restrict__ BT, int ldb,
    int row0, int col0, int nkt, int tid, int wave, int lane) {
  TileAddr ta = mk_addr<RM>(A, lda, BT, ldb, row0, col0, tid, wave, lane);
  #pragma unroll
  for (int p = 0; p < 4; ++p)
    stage_to(ta, lds + p * 16384, p * 32);
  int bufc = 0, bufn = 4;   // buf index of tile t, and of tile t+4 (mod 5)
  for (int t = 0; t < nkt; ++t) {
    const int w = nkt - 1 - t;
    if (w >= 3)      { asm volatile("s_waitcnt vmcnt(12)" ::: "memory"); }
    else if (w == 2) { asm volatile("s_waitcnt vmcnt(8)" ::: "memory"); }
    else if (w == 1) { asm volatile("s_waitcnt vmcnt(4)" ::: "memory"); }
    else             { asm volatile("s_waitcnt vmcnt(0)" ::: "memory"); }
    __builtin_amdgcn_s_barrier();
    asm volatile("" ::: "memory");
    if (t + 4 < nkt) stage_to(ta, lds + bufn * 16384, (t + 4) * 32);
    compute_step(ta, lds + bufc * 16384, acc);
    bufc = (bufc == 4) ? 0 : bufc + 1;
    bufn = (bufn == 4) ? 0 : bufn + 1;
  }
}
__device__ __forceinline__ void run_unit_d4(char* lds,
    const short* A, const short* BT, short* C, int ldc,
    int tile, int tid, int wave, int lane) {
  f32x4 acc[4][4] = {};
  int row0 = (tile >> 3) * 128, col0 = (tile & 7) * 128;
  gemm128_d4<0>(lds, acc, A, 1024, BT, 1024, row0, col0, 32, tid, wave, lane);
  epi128<0, 0>(acc, C, ldc, nullptr, row0, col0, 1024, wave, lane);
}

// ===========================================================================
// 8ph core (proven r10-r12 on big GEMMs): 256x128 tile, 512 thr, 8 waves.
// BK=64; 2 fine phases per K-tile; A triple-buffered, B double-buffered;
// vmcnt(6) at Q0 (6 newest = SA(kt+1)+SB(kt+1)); vmcnt(0) final tile.
// LDS: A 3x32KB [0,98304) + B 2x16KB [98304,131072).
// ===========================================================================
template<int RM>
__device__ __forceinline__ void gemm8ph(
    char* lds, f32x4 (&acc)[4][4],
    const short* __restrict__ A, int lda,
    const short* __restrict__ BT, int ldb,
    int row0, int col0, int nkt, int tid, int wave, int lane) {
  const int wm = wave >> 1, wn = wave & 1;
  const int l16 = lane & 15, kg = (lane >> 4) & 3;

  const short* aP[2][2];
  #pragma unroll
  for (int l = 0; l < 2; ++l) {
    int G = l * 512 + tid;
    int rp = G >> 3, gs = (G & 7) ^ (rp & 7);
    #pragma unroll
    for (int h = 0; h < 2; ++h)
      aP[l][h] = A + (size_t)rmap<RM>(row0 + h * 128 + rp) * lda + gs * 8;
  }
  const short* bP[2];
  {
    int rp = tid >> 3, gs = (tid & 7) ^ (rp & 7);
    #pragma unroll
    for (int h = 0; h < 2; ++h)
      bP[h] = BT + (size_t)(col0 + h * 64 + rp) * ldb + gs * 8;
  }

  int offA[4][2], offB[4][2];
  #pragma unroll
  for (int m = 0; m < 4; ++m) {
    int rp = (wm & 1) * 64 + m * 16 + l16;
    #pragma unroll
    for (int ks = 0; ks < 2; ++ks) {
      int gsrc = ks * 4 + kg;
      offA[m][ks] = (wm >> 1) * 16384 + (rp * 8 + (gsrc ^ (rp & 7))) * 16;
    }
  }
  #pragma unroll
  for (int n = 0; n < 4; ++n) {
    int rp = n * 16 + l16;
    #pragma unroll
    for (int ks = 0; ks < 2; ++ks) {
      int gsrc = ks * 4 + kg;
      offB[n][ks] = wn * 8192 + (rp * 8 + (gsrc ^ (rp & 7))) * 16;
    }
  }

  auto SA = [&](int kt, int ad_t, int h) {
    char* dst = lds + ad_t * 32768 + h * 16384 + tid * 16;
    gload16(dst,        aP[0][h] + kt * 64);
    gload16(dst + 8192, aP[1][h] + kt * 64);
  };
  auto SB = [&](int kt, int h) {
    gload16(lds + 98304 + (kt & 1) * 16384 + h * 8192 + tid * 16,
            bP[h] + kt * 64);
  };

  SA(0, 0, 0); SA(0, 0, 1);
  SB(0, 0); SB(0, 1);
  SA(1, 1, 0); SA(1, 1, 1);
  SB(1, 0); SB(1, 1);

  bf16x8 bR[4][2];
  int ad = 0;
  for (int kt = 0; kt < nkt; ++kt) {
    char* baseA = lds + ad * 32768;
    char* baseB = lds + 98304 + (kt & 1) * 16384;
    const int ad2 = (ad >= 1) ? ad - 1 : 2;
    // ---------------- phase Q0 ----------------
    if (kt == nkt - 1) { asm volatile("s_waitcnt vmcnt(0)" ::: "memory"); }
    else               { asm volatile("s_waitcnt vmcnt(6)" ::: "memory"); }
    __builtin_amdgcn_s_barrier();
    __builtin_amdgcn_sched_barrier(0);
    {
      #pragma unroll
      for (int n = 0; n < 4; ++n)
        #pragma unroll
        for (int ks = 0; ks < 2; ++ks)
          bR[n][ks] = *(const bf16x8*)(baseB + offB[n][ks]);
      bf16x8 aR[2][2];
      #pragma unroll
      for (int mm = 0; mm < 2; ++mm)
        #pragma unroll
        for (int ks = 0; ks < 2; ++ks)
          aR[mm][ks] = *(const bf16x8*)(baseA + offA[mm][ks]);
      if (kt + 2 < nkt) { SA(kt + 2, ad2, 0); SA(kt + 2, ad2, 1); }
      __builtin_amdgcn_s_setprio(1);
      #pragma unroll
      for (int mm = 0; mm < 2; ++mm)
        #pragma unroll
        for (int n = 0; n < 4; ++n)
          #pragma unroll
          for (int ks = 0; ks < 2; ++ks)
            acc[mm][n] = __builtin_amdgcn_mfma_f32_16x16x32_bf16(
                aR[mm][ks], bR[n][ks], acc[mm][n], 0, 0, 0);
      __builtin_amdgcn_s_setprio(0);
    }
    // ---------------- phase Q1 ----------------
    __builtin_amdgcn_s_barrier();
    __builtin_amdgcn_sched_barrier(0);
    {
      bf16x8 aR[2][2];
      #pragma unroll
      for (int mm = 0; mm < 2; ++mm)
        #pragma unroll
        for (int ks = 0; ks < 2; ++ks)
          aR[mm][ks] = *(const bf16x8*)(baseA + offA[2 + mm][ks]);
      if (kt + 2 < nkt) { SB(kt + 2, 0); SB(kt + 2, 1); }
      __builtin_amdgcn_s_setprio(1);
      #pragma unroll
      for (int mm = 0; mm < 2; ++mm)
        #pragma unroll
        for (int n = 0; n < 4; ++n)
          #pragma unroll
          for (int ks = 0; ks < 2; ++ks)
            acc[2 + mm][n] = __builtin_amdgcn_mfma_f32_16x16x32_bf16(
                aR[mm][ks], bR[n][ks], acc[2 + mm][n], 0, 0, 0);
      __builtin_amdgcn_s_setprio(0);
    }
    ad = (ad == 2) ? 0 : ad + 1;
  }
}

// 1024x1024 unit on the 8ph core: C = A * BT^T, 32 tiles of 256x128
__device__ __forceinline__ void run_unit8(char* lds,
    const short* A, const short* BT, short* C, int ldc,
    int tile, int tid, int wave, int lane) {
  f32x4 acc[4][4] = {};
  int row0 = (tile >> 3) * 256, col0 = (tile & 7) * 128;
  gemm8ph<0>(lds, acc, A, 1024, BT, 1024, row0, col0, 16, tid, wave, lane);
  epi128<0, 0>(acc, C, ldc, nullptr, row0, col0, 1024, wave, lane);
}

// Slots: 0 UT, 1 U2T, 2 U4T, 3 U8T, 4 U16T, 5 U32T, 6 U64T, 7 U128T, 8 U256T,
//        9 Ub, 10 U2, 11 U4, 12 U8, 13 U16, 14 U32, 15 U64, 16 WU1/U128, 17 Wb

// ---------------- k_prep_tc: transposes + U/W bf16 casts (no X) -------------
__global__ __launch_bounds__(256) void k_prep_tc(
    const float* __restrict__ W, const float* __restrict__ Uf,
    short* __restrict__ BTcat, short* __restrict__ slab) {
  __shared__ float tf[32][36];
  int b = blockIdx.x, t = threadIdx.x;
  if (b < 2048) {
    const float* src = (b < 1024) ? W : Uf;
    int bb = b & 1023;
    int i0 = (bb >> 5) * 32, j0 = (bb & 31) * 32;
    int r = t >> 3, c = (t & 7) * 4;
    *(f32x4*)&tf[r][c] = *(const f32x4*)(src + (size_t)(i0 + r) * 1024 + j0 + c);
    __syncthreads();
    s16x4 o;
    o.x = f2bfs(tf[c + 0][r]); o.y = f2bfs(tf[c + 1][r]);
    o.z = f2bfs(tf[c + 2][r]); o.w = f2bfs(tf[c + 3][r]);
    if (b < 1024)  // W^T -> BTcat col-block 3 (K idx 3072..4095)
      *(s16x4*)(BTcat + (size_t)(j0 + r) * 4096 + 3072 + i0 + c) = o;
    else           // U^T -> slot 0
      *(s16x4*)(slab + (size_t)(j0 + r) * 1024 + i0 + c) = o;
  } else {
    int q = b - 2048;   // first 512 = U cast (slot 9), next 512 = W cast (17)
    const float* src = (q < 512) ? Uf : W;
    short* dst = slab + (size_t)((q < 512) ? 9 : 17) * SLOT;
    int qq = q & 511;
    size_t base = (size_t)qq * 2048 + (size_t)t * 8;
    f32x4 a = *(const f32x4*)(src + base);
    f32x4 c2 = *(const f32x4*)(src + base + 4);
    bf16x8 o;
    o[0] = f2bfs(a.x);  o[1] = f2bfs(a.y);  o[2] = f2bfs(a.z);  o[3] = f2bfs(a.w);
    o[4] = f2bfs(c2.x); o[5] = f2bfs(c2.y); o[6] = f2bfs(c2.z); o[7] = f2bfs(c2.w);
    *(bf16x8*)(dst + base) = o;
  }
}

// ---------------- k_fuse<PH>: pre units (blocks 0-127) + X-cast half --------
// (r12-proven: latency-bound units ride FREE under the BW-bound cast blocks)
// PH=0: pre1 units {U2T, U2, TW1T->BTcat blk2, WU1} + X floats [0, 16.7M)
// PH=1: pre2 units {TW2T, TW3T, U4T, U4}           + X floats [16.7M, 33.5M)
// X-cast COALESCED: lane reads f32x4 at tid*4 (1KB/wave), writes s16x4 (8B).
template<int PH>
__global__ __launch_bounds__(512) void k_fuse(
    const float* __restrict__ X, short* __restrict__ XB,
    short* slab, short* BTcat) {
  __shared__ __align__(16) char lds[131072];
  int tid = threadIdx.x;
  int b = blockIdx.x;
  short* s = slab;
  if (b < 128) {
    int wave = tid >> 6, lane = tid & 63;
    int u = b >> 5, q = b & 31;
    if (PH == 0) {
      if (u == 0)       // U2T = g(UT, Ub)
        run_unit8(lds, s, s + (size_t)9 * SLOT, s + (size_t)1 * SLOT, 1024, q, tid, wave, lane);
      else if (u == 1)  // U2 = g(Ub, UT)
        run_unit8(lds, s + (size_t)9 * SLOT, s, s + (size_t)10 * SLOT, 1024, q, tid, wave, lane);
      else if (u == 2)  // TW1T = g(UT, Wb) = (WU)^T -> BTcat blk2
        run_unit8(lds, s, s + (size_t)17 * SLOT, BTcat + 2048, 4096, q, tid, wave, lane);
      else              // WU1 = g(Wb, UT) = W*U
        run_unit8(lds, s + (size_t)17 * SLOT, s, s + (size_t)16 * SLOT, 1024, q, tid, wave, lane);
    } else {
      if (u == 0)       // TW2T = g(U2T, Wb)
        run_unit8(lds, s + (size_t)1 * SLOT, s + (size_t)17 * SLOT, BTcat + 1024, 4096, q, tid, wave, lane);
      else if (u == 1)  // TW3T = g(U2T, WU1)
        run_unit8(lds, s + (size_t)1 * SLOT, s + (size_t)16 * SLOT, BTcat, 4096, q, tid, wave, lane);
      else if (u == 2)  // U4T = g(U2T, U2)
        run_unit8(lds, s + (size_t)1 * SLOT, s + (size_t)10 * SLOT, s + (size_t)2 * SLOT, 1024, q, tid, wave, lane);
      else              // U4 = g(U2, U2T)
        run_unit8(lds, s + (size_t)10 * SLOT, s + (size_t)1 * SLOT, s + (size_t)11 * SLOT, 1024, q, tid, wave, lane);
    }
  } else {
    // X-cast: block handles 8192 consecutive floats, fully coalesced
    size_t base = ((size_t)(b - 128 + PH * 2048)) * 8192;
    #pragma unroll
    for (int i = 0; i < 4; ++i) {
      size_t idx = base + (size_t)i * 2048 + (size_t)tid * 4;
      f32x4 v = *(const f32x4*)(X + idx);
      s16x4 o;
      o.x = f2bfs(v.x); o.y = f2bfs(v.y); o.z = f2bfs(v.z); o.w = f2bfs(v.w);
      *(s16x4*)(XB + idx) = o;
    }
  }
}

// ---------------- k_big: F0[8192][1024] = XB_chunk4[8192x4096] * BTcat^T ----
// PURE 256 blocks; r12-proven bijective XCD chunking: each XCD gets a
// contiguous 1024-row A-slab (L2-shared) + all B cols (FETCH ~115MB).
__global__ __launch_bounds__(512) void k_big(
    const short* __restrict__ XB, const short* __restrict__ BTcat,
    short* __restrict__ FA) {
  __shared__ __align__(16) char lds[131072];
  int tid = threadIdx.x, wave = tid >> 6, lane = tid & 63;
  int c = blockIdx.x;
  int c2 = (c & 7) * 32 + (c >> 3);          // bijective XCD chunking (256%8==0)
  f32x4 acc[4][4] = {};
  int row0 = (c2 >> 3) * 256, col0 = (c2 & 7) * 128;  // col-fastest: L2 A-reuse
  gemm8ph<3>(lds, acc, XB, 1024, BTcat, 4096, row0, col0, 64, tid, wave, lane);
  epi128<0, 0>(acc, FA, 1024, nullptr, row0, col0, 8192, wave, lane);
}

// ---------------- tree level (r12-proven): d4 combine + 0-2 side units ------
// Power chain rides the tree: level k's sides build U^(2^(k+3)) for level k+1.
template<int OUT>
__global__ __launch_bounds__(256) void k_lvl(
    const short* __restrict__ Fin, const short* __restrict__ PT,
    void* __restrict__ Fout, int M, int nComb,
    const short* __restrict__ sA0, const short* __restrict__ sB0, short* __restrict__ sC0,
    const short* __restrict__ sA1, const short* __restrict__ sB1, short* __restrict__ sC1) {
  __shared__ __align__(16) char lds[81920];
  int tid = threadIdx.x, wave = tid >> 6, lane = tid & 63;
  int b = blockIdx.x;
  if (b < nComb) {
    f32x4 acc[4][4] = {};
    int row0 = (b >> 3) * 128, col0 = (b & 7) * 128;
    gemm128_d4<2>(lds, acc, Fin, 1024, PT, 1024, row0, col0, 32, tid, wave, lane);
    epi128<2, OUT>(acc, Fout, 1024, Fin, row0, col0, M, wave, lane);
  } else {
    int q = b - nComb;
    const short* sa = (q < 64) ? sA0 : sA1;
    const short* sb = (q < 64) ? sB0 : sB1;
    short* sc = (q < 64) ? sC0 : sC1;
    run_unit_d4(lds, sa, sb, sc, 1024, q & 63, tid, wave, lane);
  }
}

extern "C" void kernel_launch(void* const* d_in, const int* in_sizes, int n_in,
                              void* d_out, int out_size, void* d_ws, size_t ws_size,
                              hipStream_t stream) {
  const float* X = (const float*)d_in[0];   // [64,512,1024] fp32
  const float* W = (const float*)d_in[1];   // [1024,1024] fp32
  const float* U = (const float*)d_in[2];   // [1024,1024] fp32
  float* outp = (float*)d_out;              // [64,1024] fp32

  char* ws = (char*)d_ws;
  short* XB    = (short*)ws;                          // [0,64MB) bf16 X
  short* FB    = (short*)ws;                          // aliases XB (dead after k_big)
  short* BTcat = (short*)(ws + ((size_t)64 << 20));   // [64,72) bf16 [1024][4096]
  short* slab  = (short*)(ws + ((size_t)72 << 20));   // [72,108) 18 x 2MB slots
  short* FA    = (short*)(ws + ((size_t)108 << 20));  // [108,124) bf16 [8192][1024]
  auto sl = [&](int i) { return slab + (size_t)i * SLOT; };

  k_prep_tc<<<3072, 256, 0, stream>>>(W, U, BTcat, slab);
  k_fuse<0><<<2176, 512, 0, stream>>>(X, XB, slab, BTcat);   // pre1 + X-cast A
  k_fuse<1><<<2176, 512, 0, stream>>>(X, XB, slab, BTcat);   // pre2 + X-cast B
  k_big<<<256, 512, 0, stream>>>(XB, BTcat, FA);

  // ph0: M=4096, nComb=256 (P=U4T); sides U8T=g(U4T,U4), U8=g(U4,U4T)
  k_lvl<0><<<384, 256, 0, stream>>>(FA, sl(2), FB, 4096, 256,
                                    sl(2), sl(11), sl(3), sl(11), sl(2), sl(12));
  // ph1: M=2048, nComb=128 (P=U8T); sides U16T, U16
  k_lvl<0><<<256, 256, 0, stream>>>(FB, sl(3), FA, 2048, 128,
                                    sl(3), sl(12), sl(4), sl(12), sl(3), sl(13));
  // ph2: M=1024, nComb=64 (P=U16T); sides U32T, U32
  k_lvl<0><<<192, 256, 0, stream>>>(FA, sl(4), FB, 1024, 64,
                                    sl(4), sl(13), sl(5), sl(13), sl(4), sl(14));
  // ph3: M=512, nComb=32 (P=U32T); sides U64T, U64
  k_lvl<0><<<160, 256, 0, stream>>>(FB, sl(5), FA, 512, 32,
                                    sl(5), sl(14), sl(6), sl(14), sl(5), sl(15));
  // ph4: M=256, nComb=16 (P=U64T); sides U128T, U128 (U128 -> slot16, WU1 dead)
  k_lvl<0><<<144, 256, 0, stream>>>(FA, sl(6), FB, 256, 16,
                                    sl(6), sl(15), sl(7), sl(15), sl(6), sl(16));
  // ph5: M=128, nComb=8 (P=U128T); side U256T=g(U128T,U128)
  k_lvl<0><<<72, 256, 0, stream>>>(FB, sl(7), FA, 128, 8,
                                   sl(7), sl(16), sl(8), nullptr, nullptr, nullptr);
  // ph6: M=64, nComb=8 (P=U256T), fp32 -> d_out
  k_lvl<1><<<8, 256, 0, stream>>>(FA, sl(8), outp, 64, 8,
                                  nullptr, nullptr, nullptr, nullptr, nullptr, nullptr);
}